// Round 8
// baseline (329.291 us; speedup 1.0000x reference)
//
#include <hip/hip_runtime.h>

// IrisSpecializedLoss — round-8: decomposed pure-streaming kernels.
// Evidence: r2 (reg), r5 (reg+fence), r7 (LDS-staged) ALL ~110-116 µs with
// HBM 17% / VALU 16% / occ 35-45% — both pipes idle; spill theory refuted
// (r7 had no reg working set, same WRITE_SIZE ~680KB = cross-XCD partial-
// line noise on scattered 4B partials, not spill). Shared structure of all
// three: one block per batch, 3 interleaved streams, barrier-punctuated
// phases, <=4 blocks/CU. Fix per G11 (memory-bound): grid-stride streaming
// kernels, no barriers, no LDS tiles, max TLP:
//   K-att  : flat float4 sum(a^2) sweep (== m13 6.29TB/s pattern + 2 FMA)
//   K-ce   : quad-pixel grid-stride; ONLINE softmax (m,s rescale; ~20 live
//            regs, no x[10][4]); argmax strict-> (JAX first-max); border-
//            weighted eq; a_t gathers (att L3-warm from K-att)
//   K-rules: 1 wave/batch, coalesced targets re-read (L3-hot), mask->MSE
//   K-final: deterministic double reduce of per-block partials
// colormap identity: sum(a-onehot)^2 = sum(a^2) - 2*sum(a_t) + #pixels.

namespace {
constexpr int kB = 4096;
constexpr int kC = 10;
constexpr int kH = 30;
constexpr int kW = 30;
constexpr int kHW = kH * kW;              // 900
constexpr int kCHW = kC * kHW;            // 9000
constexpr int kQuadsPerB = kHW / 4;       // 225
constexpr int kQuads = kB * kQuadsPerB;   // 921600
constexpr int kAttF4 = kB * kCHW / 4;     // 9216000 float4s
constexpr int kGrid = 2048;               // G11: ~8 blocks/CU, grid-stride
constexpr int kThreads = 256;
constexpr int kStride = kGrid * kThreads; // 524288
}  // namespace

// ---------- K-att: flat sum-of-squares over color_attention ----------
__global__ __launch_bounds__(kThreads) void iris_att_sq(
    const float* __restrict__ att_g, float* __restrict__ cmsq_part) {
    const int tid = threadIdx.x;
    float sq = 0.f;
    for (int idx = blockIdx.x * kThreads + tid; idx < kAttF4; idx += kStride) {
        const float4 v = reinterpret_cast<const float4*>(att_g)[idx];
        sq += v.x * v.x + v.y * v.y + v.z * v.z + v.w * v.w;
    }
#pragma unroll
    for (int off = 32; off > 0; off >>= 1) sq += __shfl_down(sq, off);
    __shared__ float s[4];
    if ((tid & 63) == 0) s[tid >> 6] = sq;
    __syncthreads();
    if (tid == 0) cmsq_part[blockIdx.x] = s[0] + s[1] + s[2] + s[3];
}

// ---------- K-ce: CE + argmax + consistency + a_t gather ----------
__global__ __launch_bounds__(kThreads) void iris_ce(
    const float* __restrict__ logits_g,   // [B,C,H,W]
    const int* __restrict__ targets_g,    // [B,H,W]
    const float* __restrict__ att_g,      // [B,H,W,C]
    float* __restrict__ ce_part,          // [kGrid]
    float* __restrict__ cmat_part,        // [kGrid] sum of a_t
    unsigned* __restrict__ weq_part,      // [kGrid]
    unsigned* __restrict__ eq_part)       // [kGrid]
{
    const int tid = threadIdx.x;
    float ce_acc = 0.f, at_acc = 0.f;
    unsigned weq_acc = 0u, eq_acc = 0u;

    for (int q = blockIdx.x * kThreads + tid; q < kQuads; q += kStride) {
        const int b = q / kQuadsPerB;             // magic-mul
        const int i = q - b * kQuadsPerB;
        const int p0 = 4 * i;

        const int4 tv = *reinterpret_cast<const int4*>(targets_g + (size_t)b * kHW + p0);
        const int ta[4] = {tv.x, tv.y, tv.z, tv.w};

        // a_t gathers: 4B/pixel, att lines L3-warm from K-att
        const float* __restrict__ ap = att_g + (size_t)b * kCHW + (size_t)p0 * kC;
        at_acc += ap[0 * kC + ta[0]] + ap[1 * kC + ta[1]] +
                  ap[2 * kC + ta[2]] + ap[3 * kC + ta[3]];

        // online softmax + argmax over 10 channel-plane float4 loads;
        // live set ~20 regs: m,s,xt (f32x4) + am (i32x4) + ta + buffer.
        const float* __restrict__ lg = logits_g + (size_t)b * kCHW + p0;
        float m[4], s[4], xt[4];
        int am[4];
#pragma unroll
        for (int j = 0; j < 4; ++j) { m[j] = -3.4e38f; s[j] = 0.f; xt[j] = 0.f; am[j] = 0; }
#pragma unroll
        for (int c = 0; c < kC; ++c) {
            const float4 v = *reinterpret_cast<const float4*>(lg + c * kHW);
            const float xv[4] = {v.x, v.y, v.z, v.w};
#pragma unroll
            for (int j = 0; j < 4; ++j) {
                const bool gt = xv[j] > m[j];          // strict >: first max (JAX)
                const float mn = gt ? xv[j] : m[j];
                // exp(-3.4e38 - x) flushes to 0 -> correct first-channel init
                s[j] = s[j] * __expf(m[j] - mn) + __expf(xv[j] - mn);
                m[j] = mn;
                am[j] = gt ? c : am[j];
                xt[j] = (c == ta[j]) ? xv[j] : xt[j];  // compile-time c -> cndmask
            }
        }
#pragma unroll
        for (int j = 0; j < 4; ++j) {
            ce_acc += m[j] + __logf(s[j]) - xt[j];
            const unsigned eq = (am[j] == ta[j]) ? 1u : 0u;
            eq_acc += eq;
            const int p = p0 + j;
            const int h = p / kW;
            const int w = p - h * kW;
            weq_acc += eq * (((h == 0 || h == kH - 1) ? 1u : 2u) *
                             ((w == 0 || w == kW - 1) ? 1u : 2u));
        }
    }

#pragma unroll
    for (int off = 32; off > 0; off >>= 1) {
        ce_acc  += __shfl_down(ce_acc, off);
        at_acc  += __shfl_down(at_acc, off);
        weq_acc += __shfl_down(weq_acc, off);
        eq_acc  += __shfl_down(eq_acc, off);
    }
    __shared__ float sf[2][4];
    __shared__ unsigned su[2][4];
    const int wave = tid >> 6;
    if ((tid & 63) == 0) {
        sf[0][wave] = ce_acc; sf[1][wave] = at_acc;
        su[0][wave] = weq_acc; su[1][wave] = eq_acc;
    }
    __syncthreads();
    if (tid == 0) {
        ce_part[blockIdx.x]   = sf[0][0] + sf[0][1] + sf[0][2] + sf[0][3];
        cmat_part[blockIdx.x] = sf[1][0] + sf[1][1] + sf[1][2] + sf[1][3];
        weq_part[blockIdx.x]  = su[0][0] + su[0][1] + su[0][2] + su[0][3];
        eq_part[blockIdx.x]   = su[1][0] + su[1][1] + su[1][2] + su[1][3];
    }
}

// ---------- K-rules: one wave per batch ----------
__global__ __launch_bounds__(64) void iris_rules(
    const int* __restrict__ targets_g, const float* __restrict__ rules_g,
    float* __restrict__ rule_part) {
    const int b = blockIdx.x;
    const int lane = threadIdx.x;
    const int* __restrict__ tgt = targets_g + (size_t)b * kHW;
    unsigned mask = 0u;
    for (int k = lane; k < kHW; k += 64) mask |= 1u << tgt[k];  // coalesced dwords
#pragma unroll
    for (int off = 32; off > 0; off >>= 1) mask |= __shfl_down(mask, off);
    if (lane == 0) {
        const float* __restrict__ lr = rules_g + (size_t)b * kC;
        unsigned mrem = mask;
        float rl = 0.f;
#pragma unroll
        for (int s2 = 0; s2 < kC; ++s2) {
            float v = 0.f;
            if (mrem) {
                v = (float)(__ffs(mrem) - 1);
                mrem &= mrem - 1u;
            }
            const float d = lr[s2] - v;
            rl += d * d;
        }
        rule_part[b] = rl;
    }
}

// ---------- K-final: deterministic double reduce ----------
__global__ __launch_bounds__(1024) void iris_finalize(
    const float* __restrict__ ce_part,
    const float* __restrict__ cmat_part,
    const float* __restrict__ cmsq_part,
    const unsigned* __restrict__ weq_part,
    const unsigned* __restrict__ eq_part,
    const float* __restrict__ rule_part,
    float* __restrict__ out) {
    const int tid = threadIdx.x;
    double ce = 0.0, cma = 0.0, cms = 0.0, rl = 0.0;
    unsigned long long weq = 0ull, eqc = 0ull;
#pragma unroll
    for (int k = 0; k < 2; ++k) {
        const int i = tid + 1024 * k;
        ce  += (double)ce_part[i];
        cma += (double)cmat_part[i];
        cms += (double)cmsq_part[i];
        weq += (unsigned long long)weq_part[i];
        eqc += (unsigned long long)eq_part[i];
    }
#pragma unroll
    for (int k = 0; k < 4; ++k) rl += (double)rule_part[tid + 1024 * k];
#pragma unroll
    for (int off = 32; off > 0; off >>= 1) {
        ce  += __shfl_down(ce, off);
        cma += __shfl_down(cma, off);
        cms += __shfl_down(cms, off);
        rl  += __shfl_down(rl, off);
        weq += __shfl_down(weq, off);
        eqc += __shfl_down(eqc, off);
    }
    __shared__ double sd[4][16];
    __shared__ unsigned long long su[2][16];
    const int wave = tid >> 6;
    if ((tid & 63) == 0) {
        sd[0][wave] = ce; sd[1][wave] = cma; sd[2][wave] = cms; sd[3][wave] = rl;
        su[0][wave] = weq; su[1][wave] = eqc;
    }
    __syncthreads();
    if (tid == 0) {
        ce = 0.0; cma = 0.0; cms = 0.0; rl = 0.0; weq = 0ull; eqc = 0ull;
#pragma unroll
        for (int i = 0; i < 16; ++i) {
            ce += sd[0][i]; cma += sd[1][i]; cms += sd[2][i]; rl += sd[3][i];
            weq += su[0][i]; eqc += su[1][i];
        }
        const double npix = (double)kB * kHW;
        const double ce_m = ce / npix;
        const double cm_m = (cms - 2.0 * cma + npix) / (npix * kC);
        const double s_mean = (double)weq / ((double)kB * (kH - 1) * (kW - 1));
        const double cons = 1.0 - s_mean / 4.0;
        const double rl_m = rl / ((double)kB * kC);
        const double exact = (double)eqc;
        double total = ce_m + 0.4 * cm_m + 0.3 * cons + 0.2 * rl_m
                       - (exact / (double)kB) * 5.0;
        if (total < 0.001) total = 0.001;
        out[0] = (float)total;
        out[1] = (float)ce_m;
        out[2] = (float)cm_m;
        out[3] = (float)cons;
        out[4] = (float)rl_m;
        out[5] = (float)exact;
    }
}

extern "C" void kernel_launch(void* const* d_in, const int* in_sizes, int n_in,
                              void* d_out, int out_size, void* d_ws, size_t ws_size,
                              hipStream_t stream) {
    const float* color_output    = (const float*)d_in[0];
    const int*   targets         = (const int*)d_in[1];
    const float* color_attention = (const float*)d_in[2];
    const float* lstm_rules      = (const float*)d_in[3];
    float* out = (float*)d_out;

    // workspace: 5 x kGrid (f32/u32) + kB rules = 57.3 KB
    float*    ce_part   = (float*)d_ws;
    float*    cmat_part = ce_part + kGrid;
    float*    cmsq_part = cmat_part + kGrid;
    unsigned* weq_part  = (unsigned*)(cmsq_part + kGrid);
    unsigned* eq_part   = weq_part + kGrid;
    float*    rule_part = (float*)(eq_part + kGrid);

    // order: att sweep first (warms att in L3 for iris_ce's gathers)
    iris_att_sq<<<kGrid, kThreads, 0, stream>>>(color_attention, cmsq_part);
    iris_ce<<<kGrid, kThreads, 0, stream>>>(color_output, targets, color_attention,
                                            ce_part, cmat_part, weq_part, eq_part);
    iris_rules<<<kB, 64, 0, stream>>>(targets, lstm_rules, rule_part);
    iris_finalize<<<1, 1024, 0, stream>>>(ce_part, cmat_part, cmsq_part,
                                          weq_part, eq_part, rule_part, out);
}